// Round 5
// baseline (108.594 us; speedup 1.0000x reference)
//
#include <hip/hip_runtime.h>

#define KOBJ 256
#define NCOPY 32
#define KCHUNK 64            // k's per block (grid.y = KOBJ/KCHUNK = 4)
#define EPSF 1e-6f
#define QMIN 0.5f

struct WS {
    float4 adata[KOBJ];                    // x_alpha, y_alpha, q_alpha (0 if empty), beta_alpha
    unsigned long long key[KOBJ][NCOPY];   // privatized argmax keys (k-major for coalesced merge)
    float pay[KOBJ][NCOPY][5];             // privatized payload sums: pw + 4 components (f32)
    double acc_att[NCOPY];                 // privatized att partials
    double acc_rep[NCOPY];                 // privatized rep partials
    double acc[8];                         // 2:noise_b 3:noise_cnt 4:minb 5:nobj 6:paysum
};

__device__ inline float clipb(float b) {
    return fminf(fmaxf(b, 1e-4f), 1.0f - 1e-4f);
}

__device__ inline float wave_sum(float v) {
    #pragma unroll
    for (int o = 32; o > 0; o >>= 1) v += __shfl_down(v, o, 64);
    return v;
}

__device__ inline double wave_sum_d(double v) {
    #pragma unroll
    for (int o = 32; o > 0; o >>= 1) v += __shfl_down(v, o, 64);
    return v;
}

// ---------------- pass 1: per-object argmax of beta (privatized) + noise sums ----------------
__global__ __launch_bounds__(256) void k_pass1(const float* __restrict__ beta_in,
                                               const int* __restrict__ tidx,
                                               int n, WS* __restrict__ ws) {
    int i = blockIdx.x * 256 + threadIdx.x;
    int c = blockIdx.x & (NCOPY - 1);
    float nb = 0.f, ncnt = 0.f;
    if (i < n) {
        float b = clipb(beta_in[i]);
        int t = tidx[i];
        if (t >= 0) {
            unsigned int bits = __float_as_uint(b);  // b>0 -> bits monotone in b
            unsigned long long kv =
                ((unsigned long long)bits << 32) | (unsigned long long)(0xFFFFFFFFu - (unsigned int)i);
            atomicMax(&ws->key[t][c], kv);
        } else {
            nb = b; ncnt = 1.f;   // noise point
        }
    }
    __shared__ float s0[4], s1[4];
    float a = wave_sum(nb), cc = wave_sum(ncnt);
    int lane = threadIdx.x & 63, w = threadIdx.x >> 6;
    if (lane == 0) { s0[w] = a; s1[w] = cc; }
    __syncthreads();
    if (threadIdx.x == 0) {
        float A = s0[0] + s0[1] + s0[2] + s0[3];
        float C = s1[0] + s1[1] + s1[2] + s1[3];
        if (C != 0.f) {
            atomicAdd(&ws->acc[2], (double)A);
            atomicAdd(&ws->acc[3], (double)C);
        }
    }
}

// ---------------- pass 2: merge keys, gather alpha data per object ----------------
__global__ __launch_bounds__(256) void k_gather(const float* __restrict__ beta_in,
                                                const float2* __restrict__ ccoords,
                                                WS* __restrict__ ws) {
    int k = threadIdx.x;
    const unsigned long long* __restrict__ kr = ws->key[k];  // contiguous 256B per thread
    unsigned long long kv = 0ull;
    #pragma unroll
    for (int c = 0; c < NCOPY; ++c) {
        unsigned long long v = kr[c];
        kv = v > kv ? v : kv;
    }
    float minb = 0.f, nobj = 0.f;
    if (kv != 0ull) {
        unsigned int idx = 0xFFFFFFFFu - (unsigned int)(kv & 0xFFFFFFFFull);
        float b = clipb(beta_in[idx]);
        float at = atanhf(b);
        float qa = at * at + QMIN;
        float2 xy = ccoords[idx];
        ws->adata[k] = make_float4(xy.x, xy.y, qa, b);
        minb = 1.f - b; nobj = 1.f;
    } else {
        ws->adata[k] = make_float4(0.f, 0.f, 0.f, 0.f);
    }
    __shared__ float s0[4], s1[4];
    float a = wave_sum(minb), c = wave_sum(nobj);
    int lane = threadIdx.x & 63, w = threadIdx.x >> 6;
    if (lane == 0) { s0[w] = a; s1[w] = c; }
    __syncthreads();
    if (threadIdx.x == 0) {
        ws->acc[4] = (double)(s0[0] + s0[1] + s0[2] + s0[3]);
        ws->acc[5] = (double)(s1[0] + s1[1] + s1[2] + s1[3]);
    }
}

__device__ inline float repterm(float4 a, float cx, float cy) {
    float dx = cx - a.x, dy = cy - a.y;
    float d2e = fmaf(dx, dx, fmaf(dy, dy, EPSF));
    float s = __builtin_amdgcn_sqrtf(d2e);
    return a.z * fmaxf(1.f - s, 0.f);
}

// ---------------- pass 3: main pass, 1 point/thread x K-chunk ----------------
// grid = (ceil(n/256), KOBJ/KCHUNK) = (782, 4) = 3128 blocks -> ~12 blocks/CU
__global__ __launch_bounds__(256, 8) void k_main(const float* __restrict__ beta_in,
                                                 const float2* __restrict__ ccoords,
                                                 const float* __restrict__ energy,
                                                 const float2* __restrict__ pos,
                                                 const float* __restrict__ ptime,
                                                 const float* __restrict__ pid,
                                                 const int* __restrict__ tidx,
                                                 const float* __restrict__ tenergy,
                                                 const float2* __restrict__ tpos,
                                                 const float* __restrict__ ttime,
                                                 int n, WS* __restrict__ ws) {
    __shared__ float4 ad[KCHUNK];
    const int kbase = blockIdx.y * KCHUNK;
    if (threadIdx.x < KCHUNK) ad[threadIdx.x] = ws->adata[kbase + threadIdx.x];
    __syncthreads();

    const int i = blockIdx.x * 256 + threadIdx.x;
    const int cpy = blockIdx.x & (NCOPY - 1);
    bool valid = i < n;
    int ii = valid ? i : 0;

    float b = clipb(beta_in[ii]);
    float at = atanhf(b);
    float q = valid ? (at * at + QMIN) : 0.f;   // q=0 kills rep/att for tail lanes
    float2 xy = ccoords[ii];
    float cx = xy.x, cy = xy.y;
    int t = valid ? tidx[ii] : -1;

    float r0 = 0.f, r1 = 0.f, r2 = 0.f, r3 = 0.f;
    for (int k = 0; k < KCHUNK; k += 4) {
        float4 a0 = ad[k + 0]; float4 a1 = ad[k + 1];
        float4 a2 = ad[k + 2]; float4 a3 = ad[k + 3];
        r0 += repterm(a0, cx, cy);
        r1 += repterm(a1, cx, cy);
        r2 += repterm(a2, cx, cy);
        r3 += repterm(a3, cx, cy);
    }
    float repn = (r0 + r1) + (r2 + r3);

    float attv = 0.f;
    int tl = t - kbase;
    if (tl >= 0 && tl < KCHUNK) {           // this block's chunk owns the point's object
        float4 a = ad[tl];
        float dx = cx - a.x, dy = cy - a.y;
        float d2 = fmaf(dx, dx, dy * dy);   // att uses d2 WITHOUT eps
        repn -= repterm(a, cx, cy);         // exclude own k from repulsion
        attv = q * a.z * d2;

        if (b > 0.1f * a.w) {               // payload weight condition
            float te = tenergy[ii];
            float ste = __builtin_amdgcn_sqrtf(te + 0.001f);
            float l = fabsf(te - energy[ii]) / (ste + 1.0f);
            float d = ste * 2.0f;
            float el = (l < d) ? l * l : fmaf(2.f * d, l - d, d * d);
            float2 pp = pos[ii], tp = tpos[ii];
            float px = pp.x - tp.x, py = pp.y - tp.y;
            float pl = fmaf(px, px, py * py) * 0.01f;
            float td = ttime[ii] * 1e9f - ptime[ii];
            float tl2 = td * td;
            float s = 0.f;
            #pragma unroll
            for (int cc = 0; cc < 6; ++cc) { float v = pid[6 * ii + cc]; s = fmaf(v, v, s); }
            float cl = 1e-8f * (s * (1.f / 6.f));
            float* p5 = ws->pay[t][cpy];
            atomicAdd(p5 + 0, b);
            atomicAdd(p5 + 1, b * el);
            atomicAdd(p5 + 2, b * pl);
            atomicAdd(p5 + 3, b * tl2);
            atomicAdd(p5 + 4, b * cl);
        }
    }
    float repv = q * repn;

    __shared__ float s0[4], s1[4];
    float a = wave_sum(attv), r = wave_sum(repv);
    int lane = threadIdx.x & 63, w = threadIdx.x >> 6;
    if (lane == 0) { s0[w] = a; s1[w] = r; }
    __syncthreads();
    if (threadIdx.x == 0) {
        float A = s0[0] + s0[1] + s0[2] + s0[3];
        float R = s1[0] + s1[1] + s1[2] + s1[3];
        int c = (blockIdx.x + blockIdx.y) & (NCOPY - 1);
        if (A != 0.f) atomicAdd(&ws->acc_att[c], (double)A);
        if (R != 0.f) atomicAdd(&ws->acc_rep[c], (double)R);
    }
}

// ---------------- pass 4: parallel payload merge (32 lanes per object) ----------------
// grid = 32 blocks x 256 threads; each 32-lane group handles one k
__global__ __launch_bounds__(256) void k_merge(WS* __restrict__ ws) {
    int c = threadIdx.x & 31;
    int k = blockIdx.x * 8 + (threadIdx.x >> 5);
    const float* p = ws->pay[k][c];
    float pw = p[0];
    float s = (p[1] + p[2]) + (p[3] + p[4]);
    #pragma unroll
    for (int o = 16; o > 0; o >>= 1) {
        pw += __shfl_down(pw, o, 32);
        s  += __shfl_down(s, o, 32);
    }
    if (c == 0 && (pw != 0.f)) {
        atomicAdd(&ws->acc[6], (double)(s / (pw + 1e-6f)));
    }
}

// ---------------- pass 5: finalize scalar loss ----------------
__global__ void k_final(const WS* __restrict__ ws, float* __restrict__ out, int n) {
    int l = threadIdx.x;   // 64 threads
    double va = 0.0, vr = 0.0;
    if (l < NCOPY) { va = ws->acc_att[l]; vr = ws->acc_rep[l]; }
    va = wave_sum_d(va);
    vr = wave_sum_d(vr);
    if (l == 0) {
        double att = va / (double)n;
        double rep = vr / (double)n;
        double noise = ws->acc[2] / (ws->acc[3] + 1e-6);
        double nobj = ws->acc[5];
        double minb = ws->acc[4] / (nobj + 1e-6);
        double pay = ws->acc[6] / (nobj + 1e-6);
        out[0] = (float)(att + rep + minb + noise + pay);
    }
}

extern "C" void kernel_launch(void* const* d_in, const int* in_sizes, int n_in,
                              void* d_out, int out_size, void* d_ws, size_t ws_size,
                              hipStream_t stream) {
    const float*  pred_beta = (const float*)d_in[0];
    const float2* ccoords   = (const float2*)d_in[1];
    const float*  energy    = (const float*)d_in[2];
    const float2* pos       = (const float2*)d_in[3];
    const float*  ptime     = (const float*)d_in[4];
    const float*  pid       = (const float*)d_in[5];
    const int*    tix       = (const int*)d_in[6];
    const float*  teng      = (const float*)d_in[7];
    const float2* tpos      = (const float2*)d_in[8];
    const float*  ttime     = (const float*)d_in[9];
    int n = in_sizes[0];
    WS* ws = (WS*)d_ws;

    hipMemsetAsync(d_ws, 0, sizeof(WS), stream);

    int blocks1 = (n + 255) / 256;
    k_pass1<<<blocks1, 256, 0, stream>>>(pred_beta, tix, n, ws);
    k_gather<<<1, 256, 0, stream>>>(pred_beta, ccoords, ws);

    dim3 grid((n + 255) / 256, KOBJ / KCHUNK);
    k_main<<<grid, 256, 0, stream>>>(pred_beta, ccoords, energy, pos, ptime, pid,
                                     tix, teng, tpos, ttime, n, ws);
    k_merge<<<32, 256, 0, stream>>>(ws);
    k_final<<<1, 64, 0, stream>>>(ws, (float*)d_out, n);
}

// Round 6
// 53.685 us; speedup vs baseline: 2.0228x; 2.0228x over previous
//
#include <hip/hip_runtime.h>
#include <cstddef>

#define KOBJ 256
#define MAXB 200            // max privatized block-copies (n <= 204800)
#define KCHUNK 32           // k's per rep-block (grid.y = KOBJ/KCHUNK = 8)
#define NACC 64
#define EPSF 1e-6f
#define QMIN 0.5f

struct WS {
    unsigned long long key[KOBJ][MAXB];  // per-block argmax keys (plain stores)
    float pay[KOBJ][MAXB][5];            // per-block payload sums (plain stores)
    double acc_att[NACC];                // privatized att partials
    double acc_rep[NACC];                // privatized rep partials
    double acc[8];                       // 2:noise_beta 3:noise_cnt
    float payk[KOBJ];                    // per-object payload term
    float4 adata[KOBJ];                  // x_a, y_a, q_a (0 if empty), beta_a
    // ---- everything below is fully rewritten each call: NOT memset ----
    float4 xyq[208896];                  // cx, cy, q, clipped beta
};

__device__ inline float clipb(float b) {
    return fminf(fmaxf(b, 1e-4f), 1.0f - 1e-4f);
}

__device__ inline float wave_sum(float v) {
    #pragma unroll
    for (int o = 32; o > 0; o >>= 1) v += __shfl_down(v, o, 64);
    return v;
}

__device__ inline double wave_sum_d(double v) {
    #pragma unroll
    for (int o = 32; o > 0; o >>= 1) v += __shfl_down(v, o, 64);
    return v;
}

// ---------- pass 1: LDS-aggregated per-object argmax + xyq precompute + noise ----------
// grid = ceil(n/1024), 1024 threads
__global__ __launch_bounds__(1024) void k_pass1(const float* __restrict__ beta_in,
                                                const float2* __restrict__ ccoords,
                                                const int* __restrict__ tidx,
                                                int n, WS* __restrict__ ws) {
    __shared__ unsigned long long skey[KOBJ];
    if (threadIdx.x < KOBJ) skey[threadIdx.x] = 0ull;
    __syncthreads();

    int i = blockIdx.x * 1024 + threadIdx.x;
    float nb = 0.f, ncnt = 0.f;
    if (i < n) {
        float b = clipb(beta_in[i]);
        float at = atanhf(b);
        float q = at * at + QMIN;
        float2 xy = ccoords[i];
        ws->xyq[i] = make_float4(xy.x, xy.y, q, b);
        int t = tidx[i];
        if (t >= 0) {
            unsigned long long kv =
                ((unsigned long long)__float_as_uint(b) << 32) |
                (unsigned long long)(0xFFFFFFFFu - (unsigned int)i);
            atomicMax(&skey[t], kv);            // LDS atomic, on-CU
        } else {
            nb = b; ncnt = 1.f;                 // noise point
        }
    }
    __syncthreads();
    if (threadIdx.x < KOBJ) ws->key[threadIdx.x][blockIdx.x] = skey[threadIdx.x];

    __shared__ float s0[16], s1[16];
    float a = wave_sum(nb), c = wave_sum(ncnt);
    int lane = threadIdx.x & 63, w = threadIdx.x >> 6;
    if (lane == 0) { s0[w] = a; s1[w] = c; }
    __syncthreads();
    if (threadIdx.x == 0) {
        float A = 0.f, C = 0.f;
        #pragma unroll
        for (int j = 0; j < 16; ++j) { A += s0[j]; C += s1[j]; }
        if (C != 0.f) {
            atomicAdd(&ws->acc[2], (double)A);
            atomicAdd(&ws->acc[3], (double)C);
        }
    }
}

// ---------- pass 2: merge per-block keys -> adata ----------
// grid = KOBJ blocks x 256 threads (one block per object)
__global__ __launch_bounds__(256) void k_gather(const float* __restrict__ beta_in,
                                                const float2* __restrict__ ccoords,
                                                int ncopies, WS* __restrict__ ws) {
    int k = blockIdx.x;
    int c = threadIdx.x;
    unsigned long long kv = (c < ncopies) ? ws->key[k][c] : 0ull;
    #pragma unroll
    for (int o = 32; o > 0; o >>= 1) {
        unsigned long long v = __shfl_down(kv, o, 64);
        kv = v > kv ? v : kv;
    }
    __shared__ unsigned long long sk[4];
    int lane = threadIdx.x & 63, w = threadIdx.x >> 6;
    if (lane == 0) sk[w] = kv;
    __syncthreads();
    if (threadIdx.x == 0) {
        kv = sk[0];
        #pragma unroll
        for (int j = 1; j < 4; ++j) kv = sk[j] > kv ? sk[j] : kv;
        float4 out = make_float4(0.f, 0.f, 0.f, 0.f);
        if (kv != 0ull) {
            unsigned int idx = 0xFFFFFFFFu - (unsigned int)(kv & 0xFFFFFFFFull);
            float b = clipb(beta_in[idx]);
            float at = atanhf(b);
            float2 xy = ccoords[idx];
            out = make_float4(xy.x, xy.y, at * at + QMIN, b);
        }
        ws->adata[k] = out;
    }
}

// ---------- pass 3: O(N) att + own-k correction + LDS-aggregated payload ----------
// grid = ceil(n/1024), 1024 threads
__global__ __launch_bounds__(1024) void k_att(const float* __restrict__ energy,
                                              const float2* __restrict__ pos,
                                              const float* __restrict__ ptime,
                                              const float* __restrict__ pid,
                                              const int* __restrict__ tidx,
                                              const float* __restrict__ tenergy,
                                              const float2* __restrict__ tpos,
                                              const float* __restrict__ ttime,
                                              int n, WS* __restrict__ ws) {
    __shared__ float spay[KOBJ * 5];
    for (int j = threadIdx.x; j < KOBJ * 5; j += 1024) spay[j] = 0.f;
    __syncthreads();

    int i = blockIdx.x * 1024 + threadIdx.x;
    float attv = 0.f, corr = 0.f;
    if (i < n) {
        int t = tidx[i];
        if (t >= 0) {
            float4 P = ws->xyq[i];
            float4 a = ws->adata[t];                 // 4KB table, L1/L2-hot
            float dx = P.x - a.x, dy = P.y - a.y;
            float d2 = fmaf(dx, dx, dy * dy);        // att: NO eps
            attv = P.z * a.z * d2;
            float dist = __builtin_amdgcn_sqrtf(d2 + EPSF);
            corr = -P.z * a.z * fmaxf(1.f - dist, 0.f);   // remove own-k from repulsion

            float b = P.w;
            if (b > 0.1f * a.w) {                    // payload condition
                float te = tenergy[i];
                float ste = __builtin_amdgcn_sqrtf(te + 0.001f);
                float l = fabsf(te - energy[i]) / (ste + 1.0f);
                float d = ste * 2.0f;
                float el = (l < d) ? l * l : fmaf(2.f * d, l - d, d * d);
                float2 pp = pos[i], tp = tpos[i];
                float px = pp.x - tp.x, py = pp.y - tp.y;
                float pl = fmaf(px, px, py * py) * 0.01f;
                float td = ttime[i] * 1e9f - ptime[i];
                float tl = td * td;
                float s = 0.f;
                #pragma unroll
                for (int cc = 0; cc < 6; ++cc) { float v = pid[6 * i + cc]; s = fmaf(v, v, s); }
                float cl = 1e-8f * (s * (1.f / 6.f));
                float* sp = &spay[t * 5];
                atomicAdd(sp + 0, b);                // LDS atomics, on-CU
                atomicAdd(sp + 1, b * el);
                atomicAdd(sp + 2, b * pl);
                atomicAdd(sp + 3, b * tl);
                atomicAdd(sp + 4, b * cl);
            }
        }
    }
    __syncthreads();
    for (int j = threadIdx.x; j < KOBJ * 5; j += 1024) {
        int k = j / 5, c = j - 5 * k;
        ws->pay[k][blockIdx.x][c] = spay[j];         // plain stores, private copy
    }

    __shared__ float s0[16], s1[16];
    float a = wave_sum(attv), r = wave_sum(corr);
    int lane = threadIdx.x & 63, w = threadIdx.x >> 6;
    if (lane == 0) { s0[w] = a; s1[w] = r; }
    __syncthreads();
    if (threadIdx.x == 0) {
        float A = 0.f, R = 0.f;
        #pragma unroll
        for (int j = 0; j < 16; ++j) { A += s0[j]; R += s1[j]; }
        atomicAdd(&ws->acc_att[blockIdx.x & (NACC - 1)], (double)A);
        atomicAdd(&ws->acc_rep[blockIdx.x & (NACC - 1)], (double)R);
    }
}

// ---------- pass 4: pure N x K repulsion, branch-free, atomic-free hot loop ----------
// grid = (ceil(n/2048), KOBJ/KCHUNK), 512 threads, 4 points/thread
__global__ __launch_bounds__(512) void k_rep(int n, WS* __restrict__ ws) {
    __shared__ float4 ad[KCHUNK];
    const int kbase = blockIdx.y * KCHUNK;
    if (threadIdx.x < KCHUNK) ad[threadIdx.x] = ws->adata[kbase + threadIdx.x];
    __syncthreads();

    const int base = blockIdx.x * 2048 + threadIdx.x;
    float cx[4], cy[4], qq[4];
    #pragma unroll
    for (int p = 0; p < 4; ++p) {
        int i = base + p * 512;
        int ii = i < n ? i : 0;
        float4 P = ws->xyq[ii];
        cx[p] = P.x; cy[p] = P.y;
        qq[p] = (i < n) ? P.z : 0.f;     // q=0 kills tail lanes
    }

    float r[4] = {0.f, 0.f, 0.f, 0.f};
    #pragma unroll 4
    for (int k = 0; k < KCHUNK; ++k) {
        float4 a = ad[k];                 // uniform broadcast read
        #pragma unroll
        for (int p = 0; p < 4; ++p) {
            float dx = cx[p] - a.x, dy = cy[p] - a.y;
            float d2 = fmaf(dx, dx, fmaf(dy, dy, EPSF));
            float s = __builtin_amdgcn_sqrtf(d2);
            r[p] = fmaf(a.z, fmaxf(1.f - s, 0.f), r[p]);
        }
    }
    float repv = fmaf(qq[0], r[0], fmaf(qq[1], r[1], fmaf(qq[2], r[2], qq[3] * r[3])));

    __shared__ float s1[8];
    float rr = wave_sum(repv);
    int lane = threadIdx.x & 63, w = threadIdx.x >> 6;
    if (lane == 0) s1[w] = rr;
    __syncthreads();
    if (threadIdx.x == 0) {
        float R = 0.f;
        #pragma unroll
        for (int j = 0; j < 8; ++j) R += s1[j];
        if (R != 0.f)
            atomicAdd(&ws->acc_rep[(blockIdx.x * 8 + blockIdx.y) & (NACC - 1)], (double)R);
    }
}

// ---------- pass 5: merge payload copies per object ----------
// grid = KOBJ blocks x 256 threads
__global__ __launch_bounds__(256) void k_merge(int ncopies, WS* __restrict__ ws) {
    int k = blockIdx.x;
    float pw = 0.f, s = 0.f;
    for (int c = threadIdx.x; c < ncopies; c += 256) {
        const float* p = ws->pay[k][c];
        pw += p[0];
        s += (p[1] + p[2]) + (p[3] + p[4]);
    }
    __shared__ float s0[4], s1[4];
    float a = wave_sum(pw), b = wave_sum(s);
    int lane = threadIdx.x & 63, w = threadIdx.x >> 6;
    if (lane == 0) { s0[w] = a; s1[w] = b; }
    __syncthreads();
    if (threadIdx.x == 0) {
        float PW = s0[0] + s0[1] + s0[2] + s0[3];
        float S  = s1[0] + s1[1] + s1[2] + s1[3];
        ws->payk[k] = S / (PW + 1e-6f);   // 0 for empty k
    }
}

// ---------- pass 6: finalize ----------
__global__ __launch_bounds__(256) void k_final(const WS* __restrict__ ws,
                                               float* __restrict__ out, int n) {
    int k = threadIdx.x;
    float4 a = ws->adata[k];
    float occ = (a.z != 0.f) ? 1.f : 0.f;
    float mb = occ * (1.f - a.w);
    float pv = ws->payk[k];
    double da = (k < NACC) ? ws->acc_att[k] : 0.0;
    double dr = (k < NACC) ? ws->acc_rep[k] : 0.0;

    float o = wave_sum(occ), m = wave_sum(mb), p = wave_sum(pv);
    double A = wave_sum_d(da), R = wave_sum_d(dr);
    __shared__ float so[4], sm[4], sp[4];
    __shared__ double sa[4], sr[4];
    int lane = threadIdx.x & 63, w = threadIdx.x >> 6;
    if (lane == 0) { so[w] = o; sm[w] = m; sp[w] = p; sa[w] = A; sr[w] = R; }
    __syncthreads();
    if (threadIdx.x == 0) {
        float O = so[0] + so[1] + so[2] + so[3];
        float M = sm[0] + sm[1] + sm[2] + sm[3];
        float P = sp[0] + sp[1] + sp[2] + sp[3];
        double At = sa[0] + sa[1] + sa[2] + sa[3];
        double Rt = sr[0] + sr[1] + sr[2] + sr[3];
        double noise = ws->acc[2] / (ws->acc[3] + 1e-6);
        double nobj = (double)O;
        out[0] = (float)(At / n + Rt / n + (double)M / (nobj + 1e-6) + noise +
                         (double)P / (nobj + 1e-6));
    }
}

extern "C" void kernel_launch(void* const* d_in, const int* in_sizes, int n_in,
                              void* d_out, int out_size, void* d_ws, size_t ws_size,
                              hipStream_t stream) {
    const float*  pred_beta = (const float*)d_in[0];
    const float2* ccoords   = (const float2*)d_in[1];
    const float*  energy    = (const float*)d_in[2];
    const float2* pos       = (const float2*)d_in[3];
    const float*  ptime     = (const float*)d_in[4];
    const float*  pid       = (const float*)d_in[5];
    const int*    tix       = (const int*)d_in[6];
    const float*  teng      = (const float*)d_in[7];
    const float2* tpos      = (const float2*)d_in[8];
    const float*  ttime     = (const float*)d_in[9];
    int n = in_sizes[0];
    WS* ws = (WS*)d_ws;

    // zero only the accumulator regions (xyq is fully rewritten each call)
    hipMemsetAsync(d_ws, 0, offsetof(WS, xyq), stream);

    int nb = (n + 1023) / 1024;            // = 196 block-copies (<= MAXB)
    k_pass1<<<nb, 1024, 0, stream>>>(pred_beta, ccoords, tix, n, ws);
    k_gather<<<KOBJ, 256, 0, stream>>>(pred_beta, ccoords, nb, ws);
    k_att<<<nb, 1024, 0, stream>>>(energy, pos, ptime, pid, tix, teng, tpos, ttime, n, ws);
    dim3 grep((n + 2047) / 2048, KOBJ / KCHUNK);
    k_rep<<<grep, 512, 0, stream>>>(n, ws);
    k_merge<<<KOBJ, 256, 0, stream>>>(nb, ws);
    k_final<<<1, 256, 0, stream>>>(ws, (float*)d_out, n);
}

// Round 7
// 52.793 us; speedup vs baseline: 2.0570x; 1.0169x over previous
//
#include <hip/hip_runtime.h>
#include <cstddef>

#define KOBJ 256
#define MAXB 200            // max privatized block-copies (n <= 204800)
#define KCHUNK 32           // k's per rep-block (grid.y = KOBJ/KCHUNK = 8)
#define NACC 64
#define EPSF 1e-6f
#define QMIN 0.5f

struct WS {
    // ---- memset region: only atomicAdd targets (1088 B) ----
    double acc_att[NACC];                // privatized att partials
    double acc_rep[NACC];                // privatized rep partials
    double acc[8];                       // 2:noise_beta 3:noise_cnt
    // ---- everything below is fully rewritten each call: NOT memset ----
    unsigned long long key[KOBJ][MAXB];  // per-block argmax keys (plain stores)
    float pay[KOBJ][MAXB][5];            // per-block payload sums (plain stores)
    float payk[KOBJ];                    // per-object payload term
    float4 adata[KOBJ];                  // x_a, y_a, q_a (0 if empty), beta_a
    float4 xyq[208896];                  // cx, cy, q, clipped beta
};

__device__ inline float clipb(float b) {
    return fminf(fmaxf(b, 1e-4f), 1.0f - 1e-4f);
}

__device__ inline float wave_sum(float v) {
    #pragma unroll
    for (int o = 32; o > 0; o >>= 1) v += __shfl_down(v, o, 64);
    return v;
}

__device__ inline double wave_sum_d(double v) {
    #pragma unroll
    for (int o = 32; o > 0; o >>= 1) v += __shfl_down(v, o, 64);
    return v;
}

// ---------- pass 1: LDS-aggregated per-object argmax + xyq precompute + noise ----------
// grid = ceil(n/1024), 1024 threads
__global__ __launch_bounds__(1024) void k_pass1(const float* __restrict__ beta_in,
                                                const float2* __restrict__ ccoords,
                                                const int* __restrict__ tidx,
                                                int n, WS* __restrict__ ws) {
    __shared__ unsigned long long skey[KOBJ];
    if (threadIdx.x < KOBJ) skey[threadIdx.x] = 0ull;
    __syncthreads();

    int i = blockIdx.x * 1024 + threadIdx.x;
    float nb = 0.f, ncnt = 0.f;
    if (i < n) {
        float b = clipb(beta_in[i]);
        float at = atanhf(b);
        float q = at * at + QMIN;
        float2 xy = ccoords[i];
        ws->xyq[i] = make_float4(xy.x, xy.y, q, b);
        int t = tidx[i];
        if (t >= 0) {
            unsigned long long kv =
                ((unsigned long long)__float_as_uint(b) << 32) |
                (unsigned long long)(0xFFFFFFFFu - (unsigned int)i);
            atomicMax(&skey[t], kv);            // LDS atomic, on-CU
        } else {
            nb = b; ncnt = 1.f;                 // noise point
        }
    }
    __syncthreads();
    if (threadIdx.x < KOBJ) ws->key[threadIdx.x][blockIdx.x] = skey[threadIdx.x];

    __shared__ float s0[16], s1[16];
    float a = wave_sum(nb), c = wave_sum(ncnt);
    int lane = threadIdx.x & 63, w = threadIdx.x >> 6;
    if (lane == 0) { s0[w] = a; s1[w] = c; }
    __syncthreads();
    if (threadIdx.x == 0) {
        float A = 0.f, C = 0.f;
        #pragma unroll
        for (int j = 0; j < 16; ++j) { A += s0[j]; C += s1[j]; }
        if (C != 0.f) {
            atomicAdd(&ws->acc[2], (double)A);
            atomicAdd(&ws->acc[3], (double)C);
        }
    }
}

// ---------- pass 2: merge per-block keys -> adata ----------
// grid = KOBJ blocks x 256 threads (one block per object)
__global__ __launch_bounds__(256) void k_gather(const float* __restrict__ beta_in,
                                                const float2* __restrict__ ccoords,
                                                int ncopies, WS* __restrict__ ws) {
    int k = blockIdx.x;
    int c = threadIdx.x;
    unsigned long long kv = (c < ncopies) ? ws->key[k][c] : 0ull;
    #pragma unroll
    for (int o = 32; o > 0; o >>= 1) {
        unsigned long long v = __shfl_down(kv, o, 64);
        kv = v > kv ? v : kv;
    }
    __shared__ unsigned long long sk[4];
    int lane = threadIdx.x & 63, w = threadIdx.x >> 6;
    if (lane == 0) sk[w] = kv;
    __syncthreads();
    if (threadIdx.x == 0) {
        kv = sk[0];
        #pragma unroll
        for (int j = 1; j < 4; ++j) kv = sk[j] > kv ? sk[j] : kv;
        float4 out = make_float4(0.f, 0.f, 0.f, 0.f);
        if (kv != 0ull) {
            unsigned int idx = 0xFFFFFFFFu - (unsigned int)(kv & 0xFFFFFFFFull);
            float b = clipb(beta_in[idx]);
            float at = atanhf(b);
            float2 xy = ccoords[idx];
            out = make_float4(xy.x, xy.y, at * at + QMIN, b);
        }
        ws->adata[k] = out;
    }
}

// ---------- pass 3: O(N) att + own-k correction + LDS-aggregated payload ----------
// grid = ceil(n/1024), 1024 threads
__global__ __launch_bounds__(1024) void k_att(const float* __restrict__ energy,
                                              const float2* __restrict__ pos,
                                              const float* __restrict__ ptime,
                                              const float* __restrict__ pid,
                                              const int* __restrict__ tidx,
                                              const float* __restrict__ tenergy,
                                              const float2* __restrict__ tpos,
                                              const float* __restrict__ ttime,
                                              int n, WS* __restrict__ ws) {
    __shared__ float spay[KOBJ * 5];
    for (int j = threadIdx.x; j < KOBJ * 5; j += 1024) spay[j] = 0.f;
    __syncthreads();

    int i = blockIdx.x * 1024 + threadIdx.x;
    float attv = 0.f, corr = 0.f;
    if (i < n) {
        int t = tidx[i];
        if (t >= 0) {
            float4 P = ws->xyq[i];
            float4 a = ws->adata[t];                 // 4KB table, L1/L2-hot
            float dx = P.x - a.x, dy = P.y - a.y;
            float d2 = fmaf(dx, dx, dy * dy);        // att: NO eps
            attv = P.z * a.z * d2;
            float dist = __builtin_amdgcn_sqrtf(d2 + EPSF);
            corr = -P.z * a.z * fmaxf(1.f - dist, 0.f);   // remove own-k from repulsion

            float b = P.w;
            if (b > 0.1f * a.w) {                    // payload condition
                float te = tenergy[i];
                float ste = __builtin_amdgcn_sqrtf(te + 0.001f);
                float l = fabsf(te - energy[i]) / (ste + 1.0f);
                float d = ste * 2.0f;
                float el = (l < d) ? l * l : fmaf(2.f * d, l - d, d * d);
                float2 pp = pos[i], tp = tpos[i];
                float px = pp.x - tp.x, py = pp.y - tp.y;
                float pl = fmaf(px, px, py * py) * 0.01f;
                float td = ttime[i] * 1e9f - ptime[i];
                float tl = td * td;
                float s = 0.f;
                #pragma unroll
                for (int cc = 0; cc < 6; ++cc) { float v = pid[6 * i + cc]; s = fmaf(v, v, s); }
                float cl = 1e-8f * (s * (1.f / 6.f));
                float* sp = &spay[t * 5];
                atomicAdd(sp + 0, b);                // LDS atomics, on-CU
                atomicAdd(sp + 1, b * el);
                atomicAdd(sp + 2, b * pl);
                atomicAdd(sp + 3, b * tl);
                atomicAdd(sp + 4, b * cl);
            }
        }
    }
    __syncthreads();
    for (int j = threadIdx.x; j < KOBJ * 5; j += 1024) {
        int k = j / 5, c = j - 5 * k;
        ws->pay[k][blockIdx.x][c] = spay[j];         // plain stores, private copy
    }

    __shared__ float s0[16], s1[16];
    float a = wave_sum(attv), r = wave_sum(corr);
    int lane = threadIdx.x & 63, w = threadIdx.x >> 6;
    if (lane == 0) { s0[w] = a; s1[w] = r; }
    __syncthreads();
    if (threadIdx.x == 0) {
        float A = 0.f, R = 0.f;
        #pragma unroll
        for (int j = 0; j < 16; ++j) { A += s0[j]; R += s1[j]; }
        atomicAdd(&ws->acc_att[blockIdx.x & (NACC - 1)], (double)A);
        atomicAdd(&ws->acc_rep[blockIdx.x & (NACC - 1)], (double)R);
    }
}

// ---------- pass 4: pure N x K repulsion, branch-free, atomic-free hot loop ----------
// grid = (ceil(n/2048), KOBJ/KCHUNK), 512 threads, 4 points/thread
__global__ __launch_bounds__(512) void k_rep(int n, WS* __restrict__ ws) {
    __shared__ float4 ad[KCHUNK];
    const int kbase = blockIdx.y * KCHUNK;
    if (threadIdx.x < KCHUNK) ad[threadIdx.x] = ws->adata[kbase + threadIdx.x];
    __syncthreads();

    const int base = blockIdx.x * 2048 + threadIdx.x;
    float cx[4], cy[4], qq[4];
    #pragma unroll
    for (int p = 0; p < 4; ++p) {
        int i = base + p * 512;
        int ii = i < n ? i : 0;
        float4 P = ws->xyq[ii];
        cx[p] = P.x; cy[p] = P.y;
        qq[p] = (i < n) ? P.z : 0.f;     // q=0 kills tail lanes
    }

    float r[4] = {0.f, 0.f, 0.f, 0.f};
    #pragma unroll 4
    for (int k = 0; k < KCHUNK; ++k) {
        float4 a = ad[k];                 // uniform broadcast read
        #pragma unroll
        for (int p = 0; p < 4; ++p) {
            float dx = cx[p] - a.x, dy = cy[p] - a.y;
            float d2 = fmaf(dx, dx, fmaf(dy, dy, EPSF));
            float s = __builtin_amdgcn_sqrtf(d2);
            r[p] = fmaf(a.z, fmaxf(1.f - s, 0.f), r[p]);
        }
    }
    float repv = fmaf(qq[0], r[0], fmaf(qq[1], r[1], fmaf(qq[2], r[2], qq[3] * r[3])));

    __shared__ float s1[8];
    float rr = wave_sum(repv);
    int lane = threadIdx.x & 63, w = threadIdx.x >> 6;
    if (lane == 0) s1[w] = rr;
    __syncthreads();
    if (threadIdx.x == 0) {
        float R = 0.f;
        #pragma unroll
        for (int j = 0; j < 8; ++j) R += s1[j];
        if (R != 0.f)
            atomicAdd(&ws->acc_rep[(blockIdx.x * 8 + blockIdx.y) & (NACC - 1)], (double)R);
    }
}

// ---------- pass 5: merge payload copies per object ----------
// grid = KOBJ blocks x 256 threads
__global__ __launch_bounds__(256) void k_merge(int ncopies, WS* __restrict__ ws) {
    int k = blockIdx.x;
    float pw = 0.f, s = 0.f;
    for (int c = threadIdx.x; c < ncopies; c += 256) {
        const float* p = ws->pay[k][c];
        pw += p[0];
        s += (p[1] + p[2]) + (p[3] + p[4]);
    }
    __shared__ float s0[4], s1[4];
    float a = wave_sum(pw), b = wave_sum(s);
    int lane = threadIdx.x & 63, w = threadIdx.x >> 6;
    if (lane == 0) { s0[w] = a; s1[w] = b; }
    __syncthreads();
    if (threadIdx.x == 0) {
        float PW = s0[0] + s0[1] + s0[2] + s0[3];
        float S  = s1[0] + s1[1] + s1[2] + s1[3];
        ws->payk[k] = S / (PW + 1e-6f);   // 0 for empty k
    }
}

// ---------- pass 6: finalize ----------
__global__ __launch_bounds__(256) void k_final(const WS* __restrict__ ws,
                                               float* __restrict__ out, int n) {
    int k = threadIdx.x;
    float4 a = ws->adata[k];
    float occ = (a.z != 0.f) ? 1.f : 0.f;
    float mb = occ * (1.f - a.w);
    float pv = ws->payk[k];
    double da = (k < NACC) ? ws->acc_att[k] : 0.0;
    double dr = (k < NACC) ? ws->acc_rep[k] : 0.0;

    float o = wave_sum(occ), m = wave_sum(mb), p = wave_sum(pv);
    double A = wave_sum_d(da), R = wave_sum_d(dr);
    __shared__ float so[4], sm[4], sp[4];
    __shared__ double sa[4], sr[4];
    int lane = threadIdx.x & 63, w = threadIdx.x >> 6;
    if (lane == 0) { so[w] = o; sm[w] = m; sp[w] = p; sa[w] = A; sr[w] = R; }
    __syncthreads();
    if (threadIdx.x == 0) {
        float O = so[0] + so[1] + so[2] + so[3];
        float M = sm[0] + sm[1] + sm[2] + sm[3];
        float P = sp[0] + sp[1] + sp[2] + sp[3];
        double At = sa[0] + sa[1] + sa[2] + sa[3];
        double Rt = sr[0] + sr[1] + sr[2] + sr[3];
        double noise = ws->acc[2] / (ws->acc[3] + 1e-6);
        double nobj = (double)O;
        out[0] = (float)(At / n + Rt / n + (double)M / (nobj + 1e-6) + noise +
                         (double)P / (nobj + 1e-6));
    }
}

extern "C" void kernel_launch(void* const* d_in, const int* in_sizes, int n_in,
                              void* d_out, int out_size, void* d_ws, size_t ws_size,
                              hipStream_t stream) {
    const float*  pred_beta = (const float*)d_in[0];
    const float2* ccoords   = (const float2*)d_in[1];
    const float*  energy    = (const float*)d_in[2];
    const float2* pos       = (const float2*)d_in[3];
    const float*  ptime     = (const float*)d_in[4];
    const float*  pid       = (const float*)d_in[5];
    const int*    tix       = (const int*)d_in[6];
    const float*  teng      = (const float*)d_in[7];
    const float2* tpos      = (const float2*)d_in[8];
    const float*  ttime     = (const float*)d_in[9];
    int n = in_sizes[0];
    WS* ws = (WS*)d_ws;

    // zero ONLY the atomicAdd accumulators (1088 B); key/pay/payk/adata/xyq
    // are fully rewritten every call
    hipMemsetAsync(d_ws, 0, offsetof(WS, key), stream);

    int nb = (n + 1023) / 1024;            // = 196 block-copies (<= MAXB)
    k_pass1<<<nb, 1024, 0, stream>>>(pred_beta, ccoords, tix, n, ws);
    k_gather<<<KOBJ, 256, 0, stream>>>(pred_beta, ccoords, nb, ws);
    k_att<<<nb, 1024, 0, stream>>>(energy, pos, ptime, pid, tix, teng, tpos, ttime, n, ws);
    dim3 grep((n + 2047) / 2048, KOBJ / KCHUNK);
    k_rep<<<grep, 512, 0, stream>>>(n, ws);
    k_merge<<<KOBJ, 256, 0, stream>>>(nb, ws);
    k_final<<<1, 256, 0, stream>>>(ws, (float*)d_out, n);
}

// Round 8
// 45.055 us; speedup vs baseline: 2.4103x; 1.1717x over previous
//
#include <hip/hip_runtime.h>

#define KOBJ 256
#define MAXB 200            // max privatized block-copies (n <= 204800)
#define KCHUNK 32           // k's per rep-block (grid.y = KOBJ/KCHUNK = 8)
#define MAXREP 1024         // max rep-grid blocks (98*8 = 784 used)
#define EPSF 1e-6f
#define QMIN 0.5f

// NO memset needed: every field below is plain-stored by a unique writer
// before it is read; k_final only reads the exact counts written this call.
struct WS {
    float att_part[MAXB];                // per-k_att-block att partials
    float corr_part[MAXB];               // per-k_att-block own-k rep corrections
    float noiseb_part[MAXB];             // per-k_pass1-block noise beta sums
    float noisec_part[MAXB];             // per-k_pass1-block noise counts
    float rep_part[MAXREP];              // per-k_rep-block rep partials
    unsigned long long key[KOBJ][MAXB];  // per-block argmax keys (plain stores)
    float pay[KOBJ][MAXB][5];            // per-block payload sums (plain stores)
    float payk[KOBJ];                    // per-object payload term
    float4 adata[KOBJ];                  // x_a, y_a, q_a (0 if empty), beta_a
    float4 xyq[208896];                  // cx, cy, q, clipped beta
};

__device__ inline float clipb(float b) {
    return fminf(fmaxf(b, 1e-4f), 1.0f - 1e-4f);
}

__device__ inline float wave_sum(float v) {
    #pragma unroll
    for (int o = 32; o > 0; o >>= 1) v += __shfl_down(v, o, 64);
    return v;
}

__device__ inline double wave_sum_d(double v) {
    #pragma unroll
    for (int o = 32; o > 0; o >>= 1) v += __shfl_down(v, o, 64);
    return v;
}

// ---------- pass 1: LDS-aggregated per-object argmax + xyq precompute + noise ----------
// grid = ceil(n/1024), 1024 threads
__global__ __launch_bounds__(1024) void k_pass1(const float* __restrict__ beta_in,
                                                const float2* __restrict__ ccoords,
                                                const int* __restrict__ tidx,
                                                int n, WS* __restrict__ ws) {
    __shared__ unsigned long long skey[KOBJ];
    if (threadIdx.x < KOBJ) skey[threadIdx.x] = 0ull;
    __syncthreads();

    int i = blockIdx.x * 1024 + threadIdx.x;
    float nb = 0.f, ncnt = 0.f;
    if (i < n) {
        float b = clipb(beta_in[i]);
        float at = atanhf(b);
        float q = at * at + QMIN;
        float2 xy = ccoords[i];
        ws->xyq[i] = make_float4(xy.x, xy.y, q, b);
        int t = tidx[i];
        if (t >= 0) {
            unsigned long long kv =
                ((unsigned long long)__float_as_uint(b) << 32) |
                (unsigned long long)(0xFFFFFFFFu - (unsigned int)i);
            atomicMax(&skey[t], kv);            // LDS atomic, on-CU
        } else {
            nb = b; ncnt = 1.f;                 // noise point
        }
    }
    __syncthreads();
    if (threadIdx.x < KOBJ) ws->key[threadIdx.x][blockIdx.x] = skey[threadIdx.x];

    __shared__ float s0[16], s1[16];
    float a = wave_sum(nb), c = wave_sum(ncnt);
    int lane = threadIdx.x & 63, w = threadIdx.x >> 6;
    if (lane == 0) { s0[w] = a; s1[w] = c; }
    __syncthreads();
    if (threadIdx.x == 0) {
        float A = 0.f, C = 0.f;
        #pragma unroll
        for (int j = 0; j < 16; ++j) { A += s0[j]; C += s1[j]; }
        ws->noiseb_part[blockIdx.x] = A;        // plain stores, no atomics
        ws->noisec_part[blockIdx.x] = C;
    }
}

// ---------- pass 2: merge per-block keys -> adata ----------
// grid = KOBJ blocks x 256 threads (one block per object)
__global__ __launch_bounds__(256) void k_gather(const float* __restrict__ beta_in,
                                                const float2* __restrict__ ccoords,
                                                int ncopies, WS* __restrict__ ws) {
    int k = blockIdx.x;
    int c = threadIdx.x;
    unsigned long long kv = (c < ncopies) ? ws->key[k][c] : 0ull;
    #pragma unroll
    for (int o = 32; o > 0; o >>= 1) {
        unsigned long long v = __shfl_down(kv, o, 64);
        kv = v > kv ? v : kv;
    }
    __shared__ unsigned long long sk[4];
    int lane = threadIdx.x & 63, w = threadIdx.x >> 6;
    if (lane == 0) sk[w] = kv;
    __syncthreads();
    if (threadIdx.x == 0) {
        kv = sk[0];
        #pragma unroll
        for (int j = 1; j < 4; ++j) kv = sk[j] > kv ? sk[j] : kv;
        float4 out = make_float4(0.f, 0.f, 0.f, 0.f);
        if (kv != 0ull) {
            unsigned int idx = 0xFFFFFFFFu - (unsigned int)(kv & 0xFFFFFFFFull);
            float b = clipb(beta_in[idx]);
            float at = atanhf(b);
            float2 xy = ccoords[idx];
            out = make_float4(xy.x, xy.y, at * at + QMIN, b);
        }
        ws->adata[k] = out;
    }
}

// ---------- pass 3: O(N) att + own-k correction + LDS-aggregated payload ----------
// grid = ceil(n/1024), 1024 threads
__global__ __launch_bounds__(1024) void k_att(const float* __restrict__ energy,
                                              const float2* __restrict__ pos,
                                              const float* __restrict__ ptime,
                                              const float* __restrict__ pid,
                                              const int* __restrict__ tidx,
                                              const float* __restrict__ tenergy,
                                              const float2* __restrict__ tpos,
                                              const float* __restrict__ ttime,
                                              int n, WS* __restrict__ ws) {
    __shared__ float spay[KOBJ * 5];
    for (int j = threadIdx.x; j < KOBJ * 5; j += 1024) spay[j] = 0.f;
    __syncthreads();

    int i = blockIdx.x * 1024 + threadIdx.x;
    float attv = 0.f, corr = 0.f;
    if (i < n) {
        int t = tidx[i];
        if (t >= 0) {
            float4 P = ws->xyq[i];
            float4 a = ws->adata[t];                 // 4KB table, L1/L2-hot
            float dx = P.x - a.x, dy = P.y - a.y;
            float d2 = fmaf(dx, dx, dy * dy);        // att: NO eps
            attv = P.z * a.z * d2;
            float dist = __builtin_amdgcn_sqrtf(d2 + EPSF);
            corr = -P.z * a.z * fmaxf(1.f - dist, 0.f);   // remove own-k from repulsion

            float b = P.w;
            if (b > 0.1f * a.w) {                    // payload condition
                float te = tenergy[i];
                float ste = __builtin_amdgcn_sqrtf(te + 0.001f);
                float l = fabsf(te - energy[i]) / (ste + 1.0f);
                float d = ste * 2.0f;
                float el = (l < d) ? l * l : fmaf(2.f * d, l - d, d * d);
                float2 pp = pos[i], tp = tpos[i];
                float px = pp.x - tp.x, py = pp.y - tp.y;
                float pl = fmaf(px, px, py * py) * 0.01f;
                float td = ttime[i] * 1e9f - ptime[i];
                float tl = td * td;
                float s = 0.f;
                #pragma unroll
                for (int cc = 0; cc < 6; ++cc) { float v = pid[6 * i + cc]; s = fmaf(v, v, s); }
                float cl = 1e-8f * (s * (1.f / 6.f));
                float* sp = &spay[t * 5];
                atomicAdd(sp + 0, b);                // LDS atomics, on-CU
                atomicAdd(sp + 1, b * el);
                atomicAdd(sp + 2, b * pl);
                atomicAdd(sp + 3, b * tl);
                atomicAdd(sp + 4, b * cl);
            }
        }
    }
    __syncthreads();
    for (int j = threadIdx.x; j < KOBJ * 5; j += 1024) {
        int k = j / 5, c = j - 5 * k;
        ws->pay[k][blockIdx.x][c] = spay[j];         // plain stores, private copy
    }

    __shared__ float s0[16], s1[16];
    float a = wave_sum(attv), r = wave_sum(corr);
    int lane = threadIdx.x & 63, w = threadIdx.x >> 6;
    if (lane == 0) { s0[w] = a; s1[w] = r; }
    __syncthreads();
    if (threadIdx.x == 0) {
        float A = 0.f, R = 0.f;
        #pragma unroll
        for (int j = 0; j < 16; ++j) { A += s0[j]; R += s1[j]; }
        ws->att_part[blockIdx.x] = A;                // plain stores, no atomics
        ws->corr_part[blockIdx.x] = R;
    }
}

// ---------- pass 4: pure N x K repulsion, branch-free, atomic-free ----------
// grid = (ceil(n/2048), KOBJ/KCHUNK), 512 threads, 4 points/thread
__global__ __launch_bounds__(512) void k_rep(int n, WS* __restrict__ ws) {
    __shared__ float4 ad[KCHUNK];
    const int kbase = blockIdx.y * KCHUNK;
    if (threadIdx.x < KCHUNK) ad[threadIdx.x] = ws->adata[kbase + threadIdx.x];
    __syncthreads();

    const int base = blockIdx.x * 2048 + threadIdx.x;
    float cx[4], cy[4], qq[4];
    #pragma unroll
    for (int p = 0; p < 4; ++p) {
        int i = base + p * 512;
        int ii = i < n ? i : 0;
        float4 P = ws->xyq[ii];
        cx[p] = P.x; cy[p] = P.y;
        qq[p] = (i < n) ? P.z : 0.f;     // q=0 kills tail lanes
    }

    float r[4] = {0.f, 0.f, 0.f, 0.f};
    #pragma unroll 4
    for (int k = 0; k < KCHUNK; ++k) {
        float4 a = ad[k];                 // uniform broadcast read
        #pragma unroll
        for (int p = 0; p < 4; ++p) {
            float dx = cx[p] - a.x, dy = cy[p] - a.y;
            float d2 = fmaf(dx, dx, fmaf(dy, dy, EPSF));
            float s = __builtin_amdgcn_sqrtf(d2);
            r[p] = fmaf(a.z, fmaxf(1.f - s, 0.f), r[p]);
        }
    }
    float repv = fmaf(qq[0], r[0], fmaf(qq[1], r[1], fmaf(qq[2], r[2], qq[3] * r[3])));

    __shared__ float s1[8];
    float rr = wave_sum(repv);
    int lane = threadIdx.x & 63, w = threadIdx.x >> 6;
    if (lane == 0) s1[w] = rr;
    __syncthreads();
    if (threadIdx.x == 0) {
        float R = 0.f;
        #pragma unroll
        for (int j = 0; j < 8; ++j) R += s1[j];
        ws->rep_part[blockIdx.y * gridDim.x + blockIdx.x] = R;   // plain store
    }
}

// ---------- pass 5: merge payload copies per object ----------
// grid = KOBJ blocks x 256 threads
__global__ __launch_bounds__(256) void k_merge(int ncopies, WS* __restrict__ ws) {
    int k = blockIdx.x;
    float pw = 0.f, s = 0.f;
    for (int c = threadIdx.x; c < ncopies; c += 256) {
        const float* p = ws->pay[k][c];
        pw += p[0];
        s += (p[1] + p[2]) + (p[3] + p[4]);
    }
    __shared__ float s0[4], s1[4];
    float a = wave_sum(pw), b = wave_sum(s);
    int lane = threadIdx.x & 63, w = threadIdx.x >> 6;
    if (lane == 0) { s0[w] = a; s1[w] = b; }
    __syncthreads();
    if (threadIdx.x == 0) {
        float PW = s0[0] + s0[1] + s0[2] + s0[3];
        float S  = s1[0] + s1[1] + s1[2] + s1[3];
        ws->payk[k] = S / (PW + 1e-6f);   // 0 for empty k
    }
}

// ---------- pass 6: reduce all per-block partials + finalize ----------
// 1 block x 256 threads
__global__ __launch_bounds__(256) void k_final(const WS* __restrict__ ws,
                                               float* __restrict__ out,
                                               int n, int nb, int nrep) {
    int k = threadIdx.x;
    float4 a = ws->adata[k];
    float occ = (a.z != 0.f) ? 1.f : 0.f;
    float mb = occ * (1.f - a.w);
    float pv = ws->payk[k];

    double att = 0.0, corr = 0.0, nbeta = 0.0, ncnt = 0.0, rep = 0.0;
    for (int j = k; j < nb; j += 256) {
        att   += (double)ws->att_part[j];
        corr  += (double)ws->corr_part[j];
        nbeta += (double)ws->noiseb_part[j];
        ncnt  += (double)ws->noisec_part[j];
    }
    for (int j = k; j < nrep; j += 256) rep += (double)ws->rep_part[j];

    float o = wave_sum(occ), m = wave_sum(mb), p = wave_sum(pv);
    double A = wave_sum_d(att), C = wave_sum_d(corr), R = wave_sum_d(rep);
    double NB = wave_sum_d(nbeta), NC = wave_sum_d(ncnt);
    __shared__ float so[4], sm[4], sp[4];
    __shared__ double sa[4], sc[4], sr[4], sb[4], sn[4];
    int lane = threadIdx.x & 63, w = threadIdx.x >> 6;
    if (lane == 0) { so[w] = o; sm[w] = m; sp[w] = p;
                     sa[w] = A; sc[w] = C; sr[w] = R; sb[w] = NB; sn[w] = NC; }
    __syncthreads();
    if (threadIdx.x == 0) {
        float O = so[0] + so[1] + so[2] + so[3];
        float M = sm[0] + sm[1] + sm[2] + sm[3];
        float P = sp[0] + sp[1] + sp[2] + sp[3];
        double At = sa[0] + sa[1] + sa[2] + sa[3];
        double Rt = (sr[0] + sr[1] + sr[2] + sr[3]) + (sc[0] + sc[1] + sc[2] + sc[3]);
        double NBt = sb[0] + sb[1] + sb[2] + sb[3];
        double NCt = sn[0] + sn[1] + sn[2] + sn[3];
        double noise = NBt / (NCt + 1e-6);
        double nobj = (double)O;
        out[0] = (float)(At / n + Rt / n + (double)M / (nobj + 1e-6) + noise +
                         (double)P / (nobj + 1e-6));
    }
}

extern "C" void kernel_launch(void* const* d_in, const int* in_sizes, int n_in,
                              void* d_out, int out_size, void* d_ws, size_t ws_size,
                              hipStream_t stream) {
    const float*  pred_beta = (const float*)d_in[0];
    const float2* ccoords   = (const float2*)d_in[1];
    const float*  energy    = (const float*)d_in[2];
    const float2* pos       = (const float2*)d_in[3];
    const float*  ptime     = (const float*)d_in[4];
    const float*  pid       = (const float*)d_in[5];
    const int*    tix       = (const int*)d_in[6];
    const float*  teng      = (const float*)d_in[7];
    const float2* tpos      = (const float2*)d_in[8];
    const float*  ttime     = (const float*)d_in[9];
    int n = in_sizes[0];
    WS* ws = (WS*)d_ws;

    // NO memset: zero global atomics remain; k_final reduces plain-stored
    // per-block partials using exact counts.
    int nb = (n + 1023) / 1024;            // = 196 block-copies (<= MAXB)
    k_pass1<<<nb, 1024, 0, stream>>>(pred_beta, ccoords, tix, n, ws);
    k_gather<<<KOBJ, 256, 0, stream>>>(pred_beta, ccoords, nb, ws);
    k_att<<<nb, 1024, 0, stream>>>(energy, pos, ptime, pid, tix, teng, tpos, ttime, n, ws);
    dim3 grep((n + 2047) / 2048, KOBJ / KCHUNK);
    k_rep<<<grep, 512, 0, stream>>>(n, ws);
    int nrep = grep.x * grep.y;            // = 784 (<= MAXREP)
    k_merge<<<KOBJ, 256, 0, stream>>>(nb, ws);
    k_final<<<1, 256, 0, stream>>>(ws, (float*)d_out, n, nb, nrep);
}